// Round 7
// baseline (247.257 us; speedup 1.0000x reference)
//
#include <hip/hip_runtime.h>
#include <stdint.h>
#include <stddef.h>

// Problem constants (fixed by the reference).
constexpr int N_NODES = 10000;
constexpr int N_EDGES = 320000;
constexpr int DIM_IN  = 128;
constexpr int DIM_H   = 256;
constexpr int DIM_C   = 32;
constexpr int DIM_OUT = 64;
constexpr int DIM_QKV = DIM_C + DIM_C + DIM_H;  // 320 : [q|k|v]
constexpr int DIM_QK  = 2 * DIM_C;              // 64  : [q|k] compact fp32
constexpr int DIM_CAT = 2 * DIM_H;              // 512 : [h|comm]
constexpr float SCALE = 0.17677669529663687f;   // 1/sqrt(32)
constexpr int MAXD = 192;   // max in-row degree; Binomial(320k,1e-4) max ~60 (17 sigma margin)

// ---------------- workspace layout (4-byte words) ----------------
constexpr size_t alignw(size_t w) { return (w + 15) & ~size_t(15); }
constexpr size_t OFF_DEG    = 0;
constexpr size_t OFF_OFFS   = alignw(OFF_DEG + N_NODES);
constexpr size_t OFF_CURSOR = alignw(OFF_OFFS + N_NODES + 1);
constexpr size_t OFF_COL    = alignw(OFF_CURSOR + N_NODES);
constexpr size_t OFF_QK     = alignw(OFF_COL + N_EDGES);                 // fp32 [N][64]
constexpr size_t OFF_BQKV   = alignw(OFF_QK + (size_t)N_NODES * DIM_QK);
// bf16 regions (ushort; 2 per word)
constexpr size_t OFF_VBF    = alignw(OFF_BQKV + DIM_QKV);                       // [N][256]
constexpr size_t OFF_XBF    = alignw(OFF_VBF + (size_t)N_NODES * DIM_H / 2);    // [N][128]
constexpr size_t OFF_CATBF  = alignw(OFF_XBF + (size_t)N_NODES * DIM_IN / 2);   // [N][512]
constexpr size_t OFF_WINT   = alignw(OFF_CATBF + (size_t)N_NODES * DIM_CAT / 2);// [256][128]
constexpr size_t OFF_WQKVT  = alignw(OFF_WINT + (size_t)DIM_H * DIM_IN / 2);    // [320][256]
constexpr size_t OFF_W1T    = alignw(OFF_WQKVT + (size_t)DIM_QKV * DIM_H / 2);  // [256][512]
constexpr size_t OFF_W2T    = alignw(OFF_W1T + (size_t)DIM_H * DIM_CAT / 2);    // [64][256]
// total ≈ 25 MB

typedef __attribute__((ext_vector_type(8))) short short8;
typedef __attribute__((ext_vector_type(4))) float floatx4;

__device__ inline unsigned short f2bf(float f) {
    uint32_t u = __builtin_bit_cast(uint32_t, f);
    uint32_t r = (u + 0x7fffu + ((u >> 16) & 1u)) >> 16;   // RNE
    return (unsigned short)r;
}
__device__ inline float bf2f_lo(uint32_t u) { return __builtin_bit_cast(float, u << 16); }
__device__ inline float bf2f_hi(uint32_t u) { return __builtin_bit_cast(float, u & 0xffff0000u); }

// ---------------- chained bf16 MFMA GEMM pair ----------------
// Phase A: T = act(A @ Bt1^T + bias1)   (A: [M][lda] bf16, Bt1: [256][K1] bf16)
//          T is a 64x256 tile kept in LDS (bf16); optionally also stored to cat_bf.
// Phase B: O = T @ Bt2^T + bias2        (Bt2: [NCH2*64][256] bf16, streamed from L2)
//          SPLITB: cols<64 -> fp32 qk[N][64], cols>=64 -> bf16 v_bf[N][256]
//          else:   fp32 out[N][NCH2*64]
// BM=64 rows/block, 4 waves; wave w owns rows [16w,16w+16).
template <int K1, int NCH2, bool RELUA, bool STOREH, bool SPLITB>
__global__ __launch_bounds__(256)
void gemm_chain(const unsigned short* __restrict__ A, int lda,
                const unsigned short* __restrict__ Bt1, const float* __restrict__ bias1,
                const unsigned short* __restrict__ Bt2, const float* __restrict__ bias2,
                unsigned short* __restrict__ cat_out,
                float* __restrict__ outF, unsigned short* __restrict__ outB, int M)
{
    constexpr int PAD = 40;    // staging row stride (bf16): 2-way banks max
    constexpr int HP  = 260;   // T-tile row stride (bf16): 16 lanes -> 16 banks on b128
    __shared__ short As[64 * PAD];
    __shared__ short Bs[256 * PAD];
    __shared__ short Ts[64 * HP];
    const int tid   = threadIdx.x;
    const int wave  = tid >> 6;
    const int lane  = tid & 63;
    const int quad  = lane >> 4;
    const int col16 = lane & 15;
    const int row0  = blockIdx.x * 64;

    floatx4 acc[16] = {};
    const int sr = tid >> 2;          // 0..63
    const int sc = (tid & 3) * 8;     // 16B k-chunk

    for (int k0 = 0; k0 < K1; k0 += 32) {
        {   // A tile: 64 rows x 32 k
            int gr = row0 + sr;
            short8 v = {};
            if (gr < M) v = *(const short8*)(A + (size_t)gr * lda + k0 + sc);
            *(short8*)(As + sr * PAD + sc) = v;
        }
        #pragma unroll
        for (int p = 0; p < 4; ++p) {  // B tile: 256 rows x 32 k
            int r = sr + p * 64;
            *(short8*)(Bs + r * PAD + sc) = *(const short8*)(Bt1 + (size_t)r * K1 + k0 + sc);
        }
        __syncthreads();
        short8 a = *(const short8*)(As + (wave * 16 + col16) * PAD + quad * 8);
        #pragma unroll
        for (int nf = 0; nf < 16; ++nf) {
            short8 b = *(const short8*)(Bs + (nf * 16 + col16) * PAD + quad * 8);
            acc[nf] = __builtin_amdgcn_mfma_f32_16x16x32_bf16(a, b, acc[nf], 0, 0, 0);
        }
        __syncthreads();
    }

    // Epilogue A: bias (+relu), bf16 -> Ts (and optionally cat_bf[:, 0:256])
    #pragma unroll
    for (int nf = 0; nf < 16; ++nf) {
        int gc = nf * 16 + col16;
        float bia = bias1[gc];
        #pragma unroll
        for (int r = 0; r < 4; ++r) {
            int lr = wave * 16 + quad * 4 + r;
            float v = acc[nf][r] + bia;
            if (RELUA) v = fmaxf(v, 0.f);
            unsigned short hv = f2bf(v);
            Ts[lr * HP + gc] = (short)hv;
            if (STOREH) {
                int gr = row0 + lr;
                if (gr < M) cat_out[(size_t)gr * DIM_CAT + gc] = hv;
            }
        }
    }
    __syncthreads();

    // Phase B: O = T @ Bt2^T, K=256, N = NCH2*64 (chunks of 64 cols)
    for (int c = 0; c < NCH2; ++c) {
        floatx4 acc2[4] = {};
        for (int k0 = 0; k0 < 256; k0 += 32) {
            short8 a = *(const short8*)(Ts + (wave * 16 + col16) * HP + k0 + quad * 8);
            #pragma unroll
            for (int nf = 0; nf < 4; ++nf) {
                int brow = c * 64 + nf * 16 + col16;
                short8 b = *(const short8*)(Bt2 + (size_t)brow * 256 + k0 + quad * 8);
                acc2[nf] = __builtin_amdgcn_mfma_f32_16x16x32_bf16(a, b, acc2[nf], 0, 0, 0);
            }
        }
        #pragma unroll
        for (int nf = 0; nf < 4; ++nf) {
            int gc = c * 64 + nf * 16 + col16;
            float bia = bias2[gc];
            #pragma unroll
            for (int r = 0; r < 4; ++r) {
                int gr = row0 + wave * 16 + quad * 4 + r;
                if (gr >= M) continue;
                float v = acc2[nf][r] + bia;
                if (SPLITB) {
                    if (gc < DIM_QK) outF[(size_t)gr * DIM_QK + gc] = v;
                    else             outB[(size_t)gr * DIM_H + (gc - DIM_QK)] = f2bf(v);
                } else {
                    outF[(size_t)gr * (NCH2 * 64) + gc] = v;
                }
            }
        }
    }
}

// ---------------- prep ----------------
__global__ void zero_deg(int* __restrict__ deg) {
    int i = blockIdx.x * blockDim.x + threadIdx.x;
    if (i < N_NODES) deg[i] = 0;
}

__global__ void prep_all(const float* __restrict__ x, const int* __restrict__ ei,
                         const float* __restrict__ W_in,
                         const float* __restrict__ Wq, const float* __restrict__ Wk,
                         const float* __restrict__ Wv,
                         const float* __restrict__ bq, const float* __restrict__ bk,
                         const float* __restrict__ bv,
                         const float* __restrict__ W1, const float* __restrict__ W2,
                         int* __restrict__ deg, unsigned short* __restrict__ xb,
                         unsigned short* __restrict__ WinT, unsigned short* __restrict__ WqkvT,
                         unsigned short* __restrict__ W1T, unsigned short* __restrict__ W2T,
                         float* __restrict__ bqkv)
{
    int i = blockIdx.x * blockDim.x + threadIdx.x;
    int stride = gridDim.x * blockDim.x;
    for (int e = i; e < N_EDGES; e += stride) atomicAdd(&deg[ei[e]], 1);
    for (int idx = i; idx < (N_NODES * DIM_IN) / 8; idx += stride) {
        float4 a = ((const float4*)x)[2 * idx];
        float4 b = ((const float4*)x)[2 * idx + 1];
        uint4 o;
        o.x = (uint32_t)f2bf(a.x) | ((uint32_t)f2bf(a.y) << 16);
        o.y = (uint32_t)f2bf(a.z) | ((uint32_t)f2bf(a.w) << 16);
        o.z = (uint32_t)f2bf(b.x) | ((uint32_t)f2bf(b.y) << 16);
        o.w = (uint32_t)f2bf(b.z) | ((uint32_t)f2bf(b.w) << 16);
        ((uint4*)xb)[idx] = o;
    }
    for (int idx = i; idx < DIM_H * DIM_IN; idx += stride) {        // WinT [256][128]
        int n = idx / DIM_IN, k = idx % DIM_IN;
        WinT[idx] = f2bf(W_in[k * DIM_H + n]);
    }
    for (int idx = i; idx < DIM_QKV * DIM_H; idx += stride) {       // WqkvT [320][256]
        int n = idx / DIM_H, k = idx % DIM_H;
        float v = (n < DIM_C)     ? Wq[k * DIM_C + n]
                : (n < 2 * DIM_C) ? Wk[k * DIM_C + (n - DIM_C)]
                                  : Wv[k * DIM_H + (n - 2 * DIM_C)];
        WqkvT[idx] = f2bf(v);
    }
    for (int idx = i; idx < DIM_H * DIM_CAT; idx += stride) {       // W1T [256][512]
        int n = idx / DIM_CAT, k = idx % DIM_CAT;
        W1T[idx] = f2bf(W1[k * DIM_H + n]);
    }
    for (int idx = i; idx < DIM_OUT * DIM_H; idx += stride) {       // W2T [64][256]
        int n = idx / DIM_H, k = idx % DIM_H;
        W2T[idx] = f2bf(W2[k * DIM_OUT + n]);
    }
    for (int idx = i; idx < DIM_QKV; idx += stride)
        bqkv[idx] = (idx < DIM_C) ? bq[idx]
                  : (idx < 2 * DIM_C) ? bk[idx - DIM_C] : bv[idx - 2 * DIM_C];
}

// Segmented single-block scan: 3 barriers total.
__global__ __launch_bounds__(256)
void scan_kernel(const int* __restrict__ deg, int* __restrict__ offs,
                 int* __restrict__ cursor, int n) {
    constexpr int SEG = 40;   // 256*40 >= 10000
    __shared__ int wsum[4], wpre[4];
    int t = threadIdx.x, lane = t & 63, wave = t >> 6;
    int base = t * SEG;
    int s = 0;
    for (int i = 0; i < SEG; ++i) { int idx = base + i; if (idx < n) s += deg[idx]; }
    int incl = s;
    #pragma unroll
    for (int d = 1; d < 64; d <<= 1) {
        int v = __shfl_up(incl, d, 64);
        if (lane >= d) incl += v;
    }
    if (lane == 63) wsum[wave] = incl;
    __syncthreads();
    if (t == 0) {
        int c = 0;
        #pragma unroll
        for (int w = 0; w < 4; ++w) { wpre[w] = c; c += wsum[w]; }
        offs[n] = c;
    }
    __syncthreads();
    int run = wpre[wave] + (incl - s);
    for (int i = 0; i < SEG; ++i) {
        int idx = base + i;
        if (idx < n) { offs[idx] = run; cursor[idx] = run; run += deg[idx]; }
    }
}

// Scatter dst ids into CSR (col only).
__global__ void edge_scatter(const int* __restrict__ ei, int* __restrict__ cursor,
                             int* __restrict__ col) {
    int e = blockIdx.x * blockDim.x + threadIdx.x;
    if (e >= N_EDGES) return;
    int src = ei[e];
    int dst = ei[N_EDGES + e];
    int pos = atomicAdd(&cursor[src], 1);
    col[pos] = dst;
}

// Fused per-row attention: dedup + q.k score + softmax + weighted v-gather -> bf16 comm.
// TWO waves per row (each handles 128 of 256 v-cols); 2 rows per 256-thread block.
__global__ __launch_bounds__(256)
void attn_row(const float* __restrict__ qk, const unsigned short* __restrict__ v_bf,
              const int* __restrict__ offs, const int* __restrict__ col,
              unsigned short* __restrict__ cat_bf) {
    __shared__ int   dstS[2][MAXD];
    __shared__ float wS[2][MAXD];
    __shared__ float qS[2][DIM_C];
    const int wid   = threadIdx.x >> 6;
    const int lane  = threadIdx.x & 63;
    const int rloc  = wid >> 1;            // 0..1
    const int half  = wid & 1;             // which 128-col half this wave owns
    const int row   = blockIdx.x * 2 + rloc;   // grid = N_NODES/2 exactly
    int beg = offs[row];
    int d = offs[row + 1] - beg;
    if (d > MAXD) d = MAXD;

    // phase 1: both waves of the pair cooperatively stage ids; wave 0 stages q
    for (int p = half * 64 + lane; p < d; p += 128) dstS[rloc][p] = col[beg + p];
    if (half == 0 && lane < DIM_C) qS[rloc][lane] = qk[(size_t)row * DIM_QK + lane];
    __syncthreads();

    // phase 2: dedup + exp(score), computed redundantly by the row's two waves
    float mysum = 0.f;
    if (d <= 64) {
        int mydst = (lane < d) ? dstS[rloc][lane] : -1;
        bool dup = false;
        #pragma unroll
        for (int k = 0; k < 63; ++k) {
            int other = __shfl(mydst, k, 64);
            dup = dup || (k < lane && other == mydst);
        }
        float w = 0.f;
        if (lane < d && !dup) {
            const float4* kp = (const float4*)(qk + (size_t)mydst * DIM_QK + DIM_C);
            float s = 0.f;
            #pragma unroll
            for (int i = 0; i < DIM_C / 4; ++i) {
                float4 b = kp[i];
                s += qS[rloc][4 * i + 0] * b.x + qS[rloc][4 * i + 1] * b.y
                   + qS[rloc][4 * i + 2] * b.z + qS[rloc][4 * i + 3] * b.w;
            }
            w = expf(s * SCALE);
        }
        wS[rloc][lane] = w;        // both waves write identical values (benign)
        mysum = w;
    } else {
        for (int p = lane; p < d; p += 64) {
            int mydst = dstS[rloc][p];
            bool dup = false;
            for (int j = 0; j < p; ++j) dup = dup || (dstS[rloc][j] == mydst);
            float w = 0.f;
            if (!dup) {
                const float4* kp = (const float4*)(qk + (size_t)mydst * DIM_QK + DIM_C);
                float s = 0.f;
                #pragma unroll
                for (int i = 0; i < DIM_C / 4; ++i) {
                    float4 b = kp[i];
                    s += qS[rloc][4 * i + 0] * b.x + qS[rloc][4 * i + 1] * b.y
                       + qS[rloc][4 * i + 2] * b.z + qS[rloc][4 * i + 3] * b.w;
                }
                w = expf(s * SCALE);
            }
            wS[rloc][p] = w;
            mysum += w;
        }
    }
    #pragma unroll
    for (int off = 32; off; off >>= 1) mysum += __shfl_down(mysum, off, 64);
    float total = __shfl(mysum, 0, 64);
    float inv = (d > 0 && total > 0.f) ? 1.0f / total : 0.f;

    // phase 3: this wave accumulates its 128-col half; lane owns 2 cols (one dword).
    // Branch-free 8-wide unroll: 8 independent dword gathers in flight.
    float accl = 0.f, acch = 0.f;
    const uint32_t* vb = (const uint32_t*)v_bf;          // v row = 128 dwords
    const int base = half * 64 + lane;
    for (int p0 = 0; p0 < d; p0 += 8) {
        int j[8]; float w[8]; uint32_t r[8];
        #pragma unroll
        for (int t = 0; t < 8; ++t) {
            int idx = p0 + t;
            bool in = idx < d;
            j[t] = in ? dstS[rloc][idx] : 0;             // pad: row 0 (L2-hot), weight 0
            w[t] = in ? wS[rloc][idx] : 0.f;
        }
        #pragma unroll
        for (int t = 0; t < 8; ++t) r[t] = vb[(size_t)j[t] * 128 + base];
        #pragma unroll
        for (int t = 0; t < 8; ++t) {
            accl += w[t] * bf2f_lo(r[t]);
            acch += w[t] * bf2f_hi(r[t]);
        }
    }
    accl *= inv; acch *= inv;
    uint32_t o = (uint32_t)f2bf(accl) | ((uint32_t)f2bf(acch) << 16);
    *(uint32_t*)(cat_bf + (size_t)row * DIM_CAT + DIM_H + half * 128 + lane * 2) = o;
}

// ---------------- launcher ----------------
extern "C" void kernel_launch(void* const* d_in, const int* in_sizes, int n_in,
                              void* d_out, int out_size, void* d_ws, size_t ws_size,
                              hipStream_t stream) {
    (void)in_sizes; (void)n_in; (void)out_size; (void)ws_size;
    const float* x    = (const float*)d_in[0];
    const int*   ei   = (const int*)d_in[1];
    const float* W_in = (const float*)d_in[2];
    const float* b_in = (const float*)d_in[3];
    const float* Wq   = (const float*)d_in[4];
    const float* bq   = (const float*)d_in[5];
    const float* Wk   = (const float*)d_in[6];
    const float* bk   = (const float*)d_in[7];
    const float* Wv   = (const float*)d_in[8];
    const float* bv   = (const float*)d_in[9];
    const float* W1   = (const float*)d_in[10];
    const float* b1   = (const float*)d_in[11];
    const float* W2   = (const float*)d_in[12];
    const float* b2   = (const float*)d_in[13];
    float* out = (float*)d_out;

    uint32_t* ws      = (uint32_t*)d_ws;
    int*      deg     = (int*)(ws + OFF_DEG);
    int*      offs    = (int*)(ws + OFF_OFFS);
    int*      cursor  = (int*)(ws + OFF_CURSOR);
    int*      col     = (int*)(ws + OFF_COL);
    float*    qk      = (float*)(ws + OFF_QK);
    float*    bqkv    = (float*)(ws + OFF_BQKV);
    unsigned short* v_bf   = (unsigned short*)(ws + OFF_VBF);
    unsigned short* x_bf   = (unsigned short*)(ws + OFF_XBF);
    unsigned short* cat_bf = (unsigned short*)(ws + OFF_CATBF);
    unsigned short* WinT   = (unsigned short*)(ws + OFF_WINT);
    unsigned short* WqkvT  = (unsigned short*)(ws + OFF_WQKVT);
    unsigned short* W1T    = (unsigned short*)(ws + OFF_W1T);
    unsigned short* W2T    = (unsigned short*)(ws + OFF_W2T);

    const int GB = (N_NODES + 63) / 64;   // 157 row-blocks

    // 0) zero deg, then fused prep + degree count
    zero_deg<<<(N_NODES + 255) / 256, 256, 0, stream>>>(deg);
    prep_all<<<640, 256, 0, stream>>>(x, ei, W_in, Wq, Wk, Wv, bq, bk, bv, W1, W2,
                                      deg, x_bf, WinT, WqkvT, W1T, W2T, bqkv);
    scan_kernel<<<1, 256, 0, stream>>>(deg, offs, cursor, N_NODES);
    edge_scatter<<<(N_EDGES + 255) / 256, 256, 0, stream>>>(ei, cursor, col);

    // 1+2) h = x@W_in+b (-> cat[:, :256] and LDS), then qkv = h@Wqkv+b (split qk/v)
    gemm_chain<DIM_IN, 5, false, true, true><<<GB, 256, 0, stream>>>(
        x_bf, DIM_IN, WinT, b_in, WqkvT, bqkv, cat_bf, qk, v_bf, N_NODES);
    // 3) fused sparse attention (dedup + softmax + bf16 v-gather), 2 waves/row
    attn_row<<<N_NODES / 2, 256, 0, stream>>>(qk, v_bf, offs, col, cat_bf);
    // 4+5) z = relu(cat@W1+b1) (LDS only), then out = z@W2 + b2
    gemm_chain<DIM_CAT, 1, true, false, false><<<GB, 256, 0, stream>>>(
        cat_bf, DIM_CAT, W1T, b1, W2T, b2, nullptr, out, nullptr, N_NODES);
}

// Round 8
// 185.310 us; speedup vs baseline: 1.3343x; 1.3343x over previous
//
#include <hip/hip_runtime.h>
#include <stdint.h>
#include <stddef.h>

// Problem constants (fixed by the reference).
constexpr int N_NODES = 10000;
constexpr int N_EDGES = 320000;
constexpr int DIM_IN  = 128;
constexpr int DIM_H   = 256;
constexpr int DIM_C   = 32;
constexpr int DIM_OUT = 64;
constexpr int DIM_QKV = DIM_C + DIM_C + DIM_H;  // 320 : [q|k|v]
constexpr int DIM_QK  = 2 * DIM_C;              // 64  : [q|k] compact fp32
constexpr int DIM_CAT = 2 * DIM_H;              // 512 : [h|comm]
constexpr float SCALE = 0.17677669529663687f;   // 1/sqrt(32)
constexpr int MAXD = 192;   // bucket capacity; Binomial(320k,1e-4) max ~66 (28 sigma margin)

// ---------------- workspace layout (4-byte words) ----------------
constexpr size_t alignw(size_t w) { return (w + 15) & ~size_t(15); }
constexpr size_t OFF_DEG    = 0;
constexpr size_t OFF_COL    = alignw(OFF_DEG + N_NODES);                 // [N][MAXD] bucket
constexpr size_t OFF_QK     = alignw(OFF_COL + (size_t)N_NODES * MAXD);  // fp32 [N][64]
constexpr size_t OFF_BQKV   = alignw(OFF_QK + (size_t)N_NODES * DIM_QK);
// bf16 regions (ushort; 2 per word)
constexpr size_t OFF_VBF    = alignw(OFF_BQKV + DIM_QKV);                       // [N][256]
constexpr size_t OFF_XBF    = alignw(OFF_VBF + (size_t)N_NODES * DIM_H / 2);    // [N][128]
constexpr size_t OFF_CATBF  = alignw(OFF_XBF + (size_t)N_NODES * DIM_IN / 2);   // [N][512]
constexpr size_t OFF_ZBF    = alignw(OFF_CATBF + (size_t)N_NODES * DIM_CAT / 2);// [N][256]
constexpr size_t OFF_WINT   = alignw(OFF_ZBF + (size_t)N_NODES * DIM_H / 2);    // [256][128]
constexpr size_t OFF_WQKVT  = alignw(OFF_WINT + (size_t)DIM_H * DIM_IN / 2);    // [320][256]
constexpr size_t OFF_W1T    = alignw(OFF_WQKVT + (size_t)DIM_QKV * DIM_H / 2);  // [256][512]
constexpr size_t OFF_W2T    = alignw(OFF_W1T + (size_t)DIM_H * DIM_CAT / 2);    // [64][256]
// total ≈ 37 MB (ws is 256 MiB)

typedef __attribute__((ext_vector_type(8))) short short8;
typedef __attribute__((ext_vector_type(4))) float floatx4;

__device__ inline unsigned short f2bf(float f) {
    uint32_t u = __builtin_bit_cast(uint32_t, f);
    uint32_t r = (u + 0x7fffu + ((u >> 16) & 1u)) >> 16;   // RNE
    return (unsigned short)r;
}
__device__ inline float bf2f_lo(uint32_t u) { return __builtin_bit_cast(float, u << 16); }
__device__ inline float bf2f_hi(uint32_t u) { return __builtin_bit_cast(float, u & 0xffff0000u); }

// ---------------- bf16 MFMA GEMM:  C = A @ Bt^T + bias ---------------- (round-6 proven)
// A: bf16 [M][K] (row stride lda), Bt: bf16 [Ncols][K] (pre-transposed weights).
// Tile BM=128 x BN=64 x BK=32; 4 waves, each 32x64 via 2x4 16x16x32 MFMA frags.
// MODE: 0 = fp32 out (ldc), 1 = bf16 out (ldc), 2 = qkv split (cols<64 -> fp32 qk[N][64],
//       cols>=64 -> bf16 v_bf[N][256]).
template <bool RELU, int MODE>
__global__ __launch_bounds__(256)
void mfma_gemm(const unsigned short* __restrict__ A, int lda,
               const unsigned short* __restrict__ Bt,
               const float* __restrict__ bias,
               float* __restrict__ Cf, unsigned short* __restrict__ Cb, int ldc,
               int M, int K)
{
    constexpr int BM = 128, BN = 64, PAD = 40;   // +8 bf16 pad: 2-way banks max
    __shared__ short As[BM * PAD];
    __shared__ short Bs[BN * PAD];
    const int tid   = threadIdx.x;
    const int wave  = tid >> 6;
    const int lane  = tid & 63;
    const int quad  = lane >> 4;
    const int col16 = lane & 15;
    const int row0  = blockIdx.y * BM;
    const int col0  = blockIdx.x * BN;

    floatx4 acc[2][4] = {};

    const int sr = tid >> 2;          // staging row 0..63
    const int sc = (tid & 3) * 8;     // staging k-chunk offset (8 bf16 = 16B)

    for (int k0 = 0; k0 < K; k0 += 32) {
        #pragma unroll
        for (int i = 0; i < 2; ++i) {            // A tile: 128 rows x 32 k
            int r = sr + i * 64;
            int gr = row0 + r;
            short8 v = {};
            if (gr < M) v = *(const short8*)(A + (size_t)gr * lda + k0 + sc);
            *(short8*)(As + r * PAD + sc) = v;
        }
        {                                         // B tile: 64 n-rows x 32 k
            short8 v = *(const short8*)(Bt + (size_t)(col0 + sr) * K + k0 + sc);
            *(short8*)(Bs + sr * PAD + sc) = v;
        }
        __syncthreads();
        short8 a0 = *(const short8*)(As + (wave * 32 + col16) * PAD + quad * 8);
        short8 a1 = *(const short8*)(As + (wave * 32 + 16 + col16) * PAD + quad * 8);
        #pragma unroll
        for (int nf = 0; nf < 4; ++nf) {
            short8 b = *(const short8*)(Bs + (nf * 16 + col16) * PAD + quad * 8);
            acc[0][nf] = __builtin_amdgcn_mfma_f32_16x16x32_bf16(a0, b, acc[0][nf], 0, 0, 0);
            acc[1][nf] = __builtin_amdgcn_mfma_f32_16x16x32_bf16(a1, b, acc[1][nf], 0, 0, 0);
        }
        __syncthreads();
    }
    #pragma unroll
    for (int mf = 0; mf < 2; ++mf)
        #pragma unroll
        for (int r = 0; r < 4; ++r) {
            int gr = row0 + wave * 32 + mf * 16 + quad * 4 + r;
            if (gr >= M) continue;
            #pragma unroll
            for (int nf = 0; nf < 4; ++nf) {
                int gc = col0 + nf * 16 + col16;
                float v = acc[mf][nf][r] + bias[gc];
                if (RELU) v = fmaxf(v, 0.f);
                if (MODE == 2) {
                    if (gc < DIM_QK) Cf[(size_t)gr * DIM_QK + gc] = v;
                    else             Cb[(size_t)gr * DIM_H + (gc - DIM_QK)] = f2bf(v);
                } else if (MODE == 1) {
                    Cb[(size_t)gr * ldc + gc] = f2bf(v);
                } else {
                    Cf[(size_t)gr * ldc + gc] = v;
                }
            }
        }
}

// ---------------- prep ----------------
__global__ void zero_deg(int* __restrict__ deg) {
    int i = blockIdx.x * blockDim.x + threadIdx.x;
    if (i < N_NODES) deg[i] = 0;
}

// Fused: edge bucket-scatter (replaces deg-count + scan + CSR scatter), x cast,
// weight transpose/cast, qkv bias concat.
__global__ void prep_all(const float* __restrict__ x, const int* __restrict__ ei,
                         const float* __restrict__ W_in,
                         const float* __restrict__ Wq, const float* __restrict__ Wk,
                         const float* __restrict__ Wv,
                         const float* __restrict__ bq, const float* __restrict__ bk,
                         const float* __restrict__ bv,
                         const float* __restrict__ W1, const float* __restrict__ W2,
                         int* __restrict__ deg, int* __restrict__ col,
                         unsigned short* __restrict__ xb,
                         unsigned short* __restrict__ WinT, unsigned short* __restrict__ WqkvT,
                         unsigned short* __restrict__ W1T, unsigned short* __restrict__ W2T,
                         float* __restrict__ bqkv)
{
    int i = blockIdx.x * blockDim.x + threadIdx.x;
    int stride = gridDim.x * blockDim.x;
    // edge scatter into per-row buckets (duplicates kept; deduped per-row in attn)
    for (int e = i; e < N_EDGES; e += stride) {
        int src = ei[e];
        int dst = ei[N_EDGES + e];
        int slot = atomicAdd(&deg[src], 1);
        if (slot < MAXD) col[src * MAXD + slot] = dst;
    }
    // x -> bf16, vectorized 8-wide
    for (int idx = i; idx < (N_NODES * DIM_IN) / 8; idx += stride) {
        float4 a = ((const float4*)x)[2 * idx];
        float4 b = ((const float4*)x)[2 * idx + 1];
        uint4 o;
        o.x = (uint32_t)f2bf(a.x) | ((uint32_t)f2bf(a.y) << 16);
        o.y = (uint32_t)f2bf(a.z) | ((uint32_t)f2bf(a.w) << 16);
        o.z = (uint32_t)f2bf(b.x) | ((uint32_t)f2bf(b.y) << 16);
        o.w = (uint32_t)f2bf(b.z) | ((uint32_t)f2bf(b.w) << 16);
        ((uint4*)xb)[idx] = o;
    }
    for (int idx = i; idx < DIM_H * DIM_IN; idx += stride) {        // WinT [256][128]
        int n = idx / DIM_IN, k = idx % DIM_IN;
        WinT[idx] = f2bf(W_in[k * DIM_H + n]);
    }
    for (int idx = i; idx < DIM_QKV * DIM_H; idx += stride) {       // WqkvT [320][256]
        int n = idx / DIM_H, k = idx % DIM_H;
        float v = (n < DIM_C)     ? Wq[k * DIM_C + n]
                : (n < 2 * DIM_C) ? Wk[k * DIM_C + (n - DIM_C)]
                                  : Wv[k * DIM_H + (n - 2 * DIM_C)];
        WqkvT[idx] = f2bf(v);
    }
    for (int idx = i; idx < DIM_H * DIM_CAT; idx += stride) {       // W1T [256][512]
        int n = idx / DIM_CAT, k = idx % DIM_CAT;
        W1T[idx] = f2bf(W1[k * DIM_H + n]);
    }
    for (int idx = i; idx < DIM_OUT * DIM_H; idx += stride) {       // W2T [64][256]
        int n = idx / DIM_H, k = idx % DIM_H;
        W2T[idx] = f2bf(W2[k * DIM_OUT + n]);
    }
    for (int idx = i; idx < DIM_QKV; idx += stride)
        bqkv[idx] = (idx < DIM_C) ? bq[idx]
                  : (idx < 2 * DIM_C) ? bk[idx - DIM_C] : bv[idx - 2 * DIM_C];
}

// Fused per-row attention: dedup + q.k score + softmax + weighted v-gather -> bf16 comm.
// One wave per row, 4 rows per block (10000 = 4 * 2500 exactly).    (round-6 proven)
// qk: fp32 [N][64] ([q|k]); v_bf: bf16 [N][256]; col: [N][MAXD] bucket; deg: raw counts.
__global__ __launch_bounds__(256)
void attn_row(const float* __restrict__ qk, const unsigned short* __restrict__ v_bf,
              const int* __restrict__ deg, const int* __restrict__ col,
              unsigned short* __restrict__ cat_bf) {
    __shared__ int   dstS[4][MAXD];
    __shared__ float wS[4][MAXD];
    __shared__ float qS[4][DIM_C];
    const int wave = threadIdx.x >> 6;
    const int lane = threadIdx.x & 63;
    const int row = blockIdx.x * 4 + wave;   // grid is exactly N_NODES/4
    int d = deg[row];
    if (d > MAXD) d = MAXD;
    const int* crow = col + (size_t)row * MAXD;

    // phase 1: stage neighbor ids + q row into LDS
    for (int p = lane; p < d; p += 64) dstS[wave][p] = crow[p];
    if (lane < DIM_C) qS[wave][lane] = qk[(size_t)row * DIM_QK + lane];
    __syncthreads();

    // phase 2: dedup (first instance wins) + exp(score)
    float mysum = 0.f;
    if (d <= 64) {
        // fast path: lane p owns neighbor p; dup test via shfl compares (pure VALU)
        int mydst = (lane < d) ? dstS[wave][lane] : -1;
        bool dup = false;
        #pragma unroll
        for (int k = 0; k < 63; ++k) {
            int other = __shfl(mydst, k, 64);
            dup = dup || (k < lane && other == mydst);
        }
        float w = 0.f;
        if (lane < d && !dup) {
            const float4* kp = (const float4*)(qk + (size_t)mydst * DIM_QK + DIM_C);
            float s = 0.f;
            #pragma unroll
            for (int i = 0; i < DIM_C / 4; ++i) {
                float4 b = kp[i];
                s += qS[wave][4 * i + 0] * b.x + qS[wave][4 * i + 1] * b.y
                   + qS[wave][4 * i + 2] * b.z + qS[wave][4 * i + 3] * b.w;
            }
            w = expf(s * SCALE);
        }
        wS[wave][lane] = w;       // lanes >= d store 0 (phase-3 tail pads safely)
        mysum = w;
    } else {
        // fallback (statistically never): strided, branch-free LDS dup scan
        for (int p = lane; p < d; p += 64) {
            int mydst = dstS[wave][p];
            bool dup = false;
            for (int j = 0; j < p; ++j) dup = dup || (dstS[wave][j] == mydst);
            float w = 0.f;
            if (!dup) {
                const float4* kp = (const float4*)(qk + (size_t)mydst * DIM_QK + DIM_C);
                float s = 0.f;
                #pragma unroll
                for (int i = 0; i < DIM_C / 4; ++i) {
                    float4 b = kp[i];
                    s += qS[wave][4 * i + 0] * b.x + qS[wave][4 * i + 1] * b.y
                       + qS[wave][4 * i + 2] * b.z + qS[wave][4 * i + 3] * b.w;
                }
                w = expf(s * SCALE);
            }
            wS[wave][p] = w;
            mysum += w;
        }
    }
    #pragma unroll
    for (int off = 32; off; off >>= 1) mysum += __shfl_down(mysum, off, 64);
    float total = __shfl(mysum, 0, 64);
    float inv = (d > 0 && total > 0.f) ? 1.0f / total : 0.f;
    __syncthreads();

    // phase 3: comm[row] = inv * sum_p w_p * v[dst_p]; lane owns 4 of 256 cols.
    // Branch-free 8-wide unroll: 8 independent gathers in flight per latency window.
    float4 acc = make_float4(0.f, 0.f, 0.f, 0.f);
    const uint2* vb = (const uint2*)v_bf;           // v row = 64 uint2
    for (int p0 = 0; p0 < d; p0 += 8) {
        int j[8]; float w[8]; uint2 r[8];
        #pragma unroll
        for (int t = 0; t < 8; ++t) {
            int idx = p0 + t;
            bool in = idx < d;
            j[t] = in ? dstS[wave][idx] : 0;        // pad: row 0 (L2-hot), weight 0
            w[t] = in ? wS[wave][idx] : 0.f;
        }
        #pragma unroll
        for (int t = 0; t < 8; ++t) r[t] = vb[(size_t)j[t] * 64 + lane];
        #pragma unroll
        for (int t = 0; t < 8; ++t) {
            acc.x += w[t] * bf2f_lo(r[t].x);
            acc.y += w[t] * bf2f_hi(r[t].x);
            acc.z += w[t] * bf2f_lo(r[t].y);
            acc.w += w[t] * bf2f_hi(r[t].y);
        }
    }
    acc.x *= inv; acc.y *= inv; acc.z *= inv; acc.w *= inv;
    uint2 o;
    o.x = (uint32_t)f2bf(acc.x) | ((uint32_t)f2bf(acc.y) << 16);
    o.y = (uint32_t)f2bf(acc.z) | ((uint32_t)f2bf(acc.w) << 16);
    *(uint2*)(cat_bf + (size_t)row * DIM_CAT + DIM_H + lane * 4) = o;
}

// ---------------- launcher ----------------
extern "C" void kernel_launch(void* const* d_in, const int* in_sizes, int n_in,
                              void* d_out, int out_size, void* d_ws, size_t ws_size,
                              hipStream_t stream) {
    (void)in_sizes; (void)n_in; (void)out_size; (void)ws_size;
    const float* x    = (const float*)d_in[0];
    const int*   ei   = (const int*)d_in[1];
    const float* W_in = (const float*)d_in[2];
    const float* b_in = (const float*)d_in[3];
    const float* Wq   = (const float*)d_in[4];
    const float* bq   = (const float*)d_in[5];
    const float* Wk   = (const float*)d_in[6];
    const float* bk   = (const float*)d_in[7];
    const float* Wv   = (const float*)d_in[8];
    const float* bv   = (const float*)d_in[9];
    const float* W1   = (const float*)d_in[10];
    const float* b1   = (const float*)d_in[11];
    const float* W2   = (const float*)d_in[12];
    const float* b2   = (const float*)d_in[13];
    float* out = (float*)d_out;

    uint32_t* ws      = (uint32_t*)d_ws;
    int*      deg     = (int*)(ws + OFF_DEG);
    int*      col     = (int*)(ws + OFF_COL);
    float*    qk      = (float*)(ws + OFF_QK);
    float*    bqkv    = (float*)(ws + OFF_BQKV);
    unsigned short* v_bf   = (unsigned short*)(ws + OFF_VBF);
    unsigned short* x_bf   = (unsigned short*)(ws + OFF_XBF);
    unsigned short* cat_bf = (unsigned short*)(ws + OFF_CATBF);
    unsigned short* z_bf   = (unsigned short*)(ws + OFF_ZBF);
    unsigned short* WinT   = (unsigned short*)(ws + OFF_WINT);
    unsigned short* WqkvT  = (unsigned short*)(ws + OFF_WQKVT);
    unsigned short* W1T    = (unsigned short*)(ws + OFF_W1T);
    unsigned short* W2T    = (unsigned short*)(ws + OFF_W2T);

    // 0) zero deg, then fused prep (edge bucket-scatter + casts + transposes)
    zero_deg<<<(N_NODES + 255) / 256, 256, 0, stream>>>(deg);
    prep_all<<<640, 256, 0, stream>>>(x, ei, W_in, Wq, Wk, Wv, bq, bk, bv, W1, W2,
                                      deg, col, x_bf, WinT, WqkvT, W1T, W2T, bqkv);

    const int MB = (N_NODES + 127) / 128;   // 79 row-blocks
    // 1) h = x@W_in + b_in -> bf16 cat[:,0:256]
    mfma_gemm<false, 1><<<dim3(DIM_H / 64, MB), 256, 0, stream>>>(
        x_bf, DIM_IN, WinT, b_in, nullptr, cat_bf, DIM_CAT, N_NODES, DIM_IN);
    // 2) qkv = h@[Wq|Wk|Wv] + b -> split: qk fp32 [N][64], v bf16 [N][256]
    mfma_gemm<false, 2><<<dim3(DIM_QKV / 64, MB), 256, 0, stream>>>(
        cat_bf, DIM_CAT, WqkvT, bqkv, qk, v_bf, 0, N_NODES, DIM_H);
    // 3) fused sparse attention (dedup + softmax + bf16 v-gather)
    attn_row<<<N_NODES / 4, 256, 0, stream>>>(qk, v_bf, deg, col, cat_bf);
    // 4) z = relu(cat@W1 + b1) -> bf16
    mfma_gemm<true, 1><<<dim3(DIM_H / 64, MB), 256, 0, stream>>>(
        cat_bf, DIM_CAT, W1T, b1, nullptr, z_bf, DIM_H, N_NODES, DIM_CAT);
    // 5) out = z@W2 + b2 -> fp32
    mfma_gemm<false, 0><<<dim3(DIM_OUT / 64, MB), 256, 0, stream>>>(
        z_bf, DIM_H, W2T, b2, out, nullptr, DIM_OUT, N_NODES, DIM_H);
}

// Round 9
// 179.508 us; speedup vs baseline: 1.3774x; 1.0323x over previous
//
#include <hip/hip_runtime.h>
#include <stdint.h>
#include <stddef.h>

// Problem constants (fixed by the reference).
constexpr int N_NODES = 10000;
constexpr int N_EDGES = 320000;
constexpr int DIM_IN  = 128;
constexpr int DIM_H   = 256;
constexpr int DIM_C   = 32;
constexpr int DIM_OUT = 64;
constexpr int DIM_QKV = DIM_C + DIM_C + DIM_H;  // 320 : [q|k|v]
constexpr int DIM_QK  = 2 * DIM_C;              // 64  : [q|k] compact fp32
constexpr int DIM_CAT = 2 * DIM_H;              // 512 : [h|comm]
constexpr float SCALE = 0.17677669529663687f;   // 1/sqrt(32)
constexpr int MAXD = 192;   // bucket capacity; Binomial(320k,1e-4) max ~66 (28 sigma margin)
constexpr float VSCALE = 64.0f;                 // fp8 v pre-scale (|v|max ~0.5 -> ~32 << 448)

#if __has_builtin(__builtin_amdgcn_cvt_pk_f32_fp8) && __has_builtin(__builtin_amdgcn_cvt_pk_fp8_f32)
#define V_FP8 1
#else
#define V_FP8 0   // fallback: bf16 v (round-8 proven path)
#endif

// ---------------- workspace layout (4-byte words) ----------------
constexpr size_t alignw(size_t w) { return (w + 15) & ~size_t(15); }
constexpr size_t OFF_DEG    = 0;
constexpr size_t OFF_COL    = alignw(OFF_DEG + N_NODES);                 // [N][MAXD] bucket
constexpr size_t OFF_QK     = alignw(OFF_COL + (size_t)N_NODES * MAXD);  // fp32 [N][64]
constexpr size_t OFF_BQKV   = alignw(OFF_QK + (size_t)N_NODES * DIM_QK);
// v region sized for the larger (bf16) variant; fp8 uses half of it.
constexpr size_t OFF_VBF    = alignw(OFF_BQKV + DIM_QKV);                       // [N][256]
constexpr size_t OFF_XBF    = alignw(OFF_VBF + (size_t)N_NODES * DIM_H / 2);    // [N][128]
constexpr size_t OFF_CATBF  = alignw(OFF_XBF + (size_t)N_NODES * DIM_IN / 2);   // [N][512]
constexpr size_t OFF_ZBF    = alignw(OFF_CATBF + (size_t)N_NODES * DIM_CAT / 2);// [N][256]
constexpr size_t OFF_WINT   = alignw(OFF_ZBF + (size_t)N_NODES * DIM_H / 2);    // [256][128]
constexpr size_t OFF_WQKVT  = alignw(OFF_WINT + (size_t)DIM_H * DIM_IN / 2);    // [320][256]
constexpr size_t OFF_W1T    = alignw(OFF_WQKVT + (size_t)DIM_QKV * DIM_H / 2);  // [256][512]
constexpr size_t OFF_W2T    = alignw(OFF_W1T + (size_t)DIM_H * DIM_CAT / 2);    // [64][256]
// total ≈ 37 MB (ws is 256 MiB)

typedef __attribute__((ext_vector_type(8))) short short8;
typedef __attribute__((ext_vector_type(4))) float floatx4;
typedef __attribute__((ext_vector_type(2))) float floatx2;

__device__ inline unsigned short f2bf(float f) {
    uint32_t u = __builtin_bit_cast(uint32_t, f);
    uint32_t r = (u + 0x7fffu + ((u >> 16) & 1u)) >> 16;   // RNE
    return (unsigned short)r;
}
__device__ inline float bf2f_lo(uint32_t u) { return __builtin_bit_cast(float, u << 16); }
__device__ inline float bf2f_hi(uint32_t u) { return __builtin_bit_cast(float, u & 0xffff0000u); }

// ---------------- bf16 MFMA GEMM:  C = A @ Bt^T + bias ---------------- (round-8 proven)
// MODE: 0 = fp32 out (ldc), 1 = bf16 out (ldc), 2 = qkv split (cols<64 -> fp32 qk[N][64],
//       cols>=64 -> v table: fp8 (V_FP8) or bf16, [N][256]).
template <bool RELU, int MODE>
__global__ __launch_bounds__(256)
void mfma_gemm(const unsigned short* __restrict__ A, int lda,
               const unsigned short* __restrict__ Bt,
               const float* __restrict__ bias,
               float* __restrict__ Cf, unsigned short* __restrict__ Cb, int ldc,
               int M, int K)
{
    constexpr int BM = 128, BN = 64, PAD = 40;   // +8 bf16 pad: 2-way banks max
    __shared__ short As[BM * PAD];
    __shared__ short Bs[BN * PAD];
    const int tid   = threadIdx.x;
    const int wave  = tid >> 6;
    const int lane  = tid & 63;
    const int quad  = lane >> 4;
    const int col16 = lane & 15;
    const int row0  = blockIdx.y * BM;
    const int col0  = blockIdx.x * BN;

    floatx4 acc[2][4] = {};

    const int sr = tid >> 2;          // staging row 0..63
    const int sc = (tid & 3) * 8;     // staging k-chunk offset (8 bf16 = 16B)

    for (int k0 = 0; k0 < K; k0 += 32) {
        #pragma unroll
        for (int i = 0; i < 2; ++i) {            // A tile: 128 rows x 32 k
            int r = sr + i * 64;
            int gr = row0 + r;
            short8 v = {};
            if (gr < M) v = *(const short8*)(A + (size_t)gr * lda + k0 + sc);
            *(short8*)(As + r * PAD + sc) = v;
        }
        {                                         // B tile: 64 n-rows x 32 k
            short8 v = *(const short8*)(Bt + (size_t)(col0 + sr) * K + k0 + sc);
            *(short8*)(Bs + sr * PAD + sc) = v;
        }
        __syncthreads();
        short8 a0 = *(const short8*)(As + (wave * 32 + col16) * PAD + quad * 8);
        short8 a1 = *(const short8*)(As + (wave * 32 + 16 + col16) * PAD + quad * 8);
        #pragma unroll
        for (int nf = 0; nf < 4; ++nf) {
            short8 b = *(const short8*)(Bs + (nf * 16 + col16) * PAD + quad * 8);
            acc[0][nf] = __builtin_amdgcn_mfma_f32_16x16x32_bf16(a0, b, acc[0][nf], 0, 0, 0);
            acc[1][nf] = __builtin_amdgcn_mfma_f32_16x16x32_bf16(a1, b, acc[1][nf], 0, 0, 0);
        }
        __syncthreads();
    }
    #pragma unroll
    for (int mf = 0; mf < 2; ++mf)
        #pragma unroll
        for (int r = 0; r < 4; ++r) {
            int gr = row0 + wave * 32 + mf * 16 + quad * 4 + r;
            if (gr >= M) continue;
            #pragma unroll
            for (int nf = 0; nf < 4; ++nf) {
                int gc = col0 + nf * 16 + col16;
                float v = acc[mf][nf][r] + bias[gc];
                if (RELU) v = fmaxf(v, 0.f);
                if (MODE == 2) {
                    if (gc < DIM_QK) {
                        Cf[(size_t)gr * DIM_QK + gc] = v;
                    } else {
#if V_FP8
                        int pk = __builtin_amdgcn_cvt_pk_fp8_f32(v * VSCALE, 0.f, 0, false);
                        ((unsigned char*)Cb)[(size_t)gr * DIM_H + (gc - DIM_QK)] =
                            (unsigned char)(pk & 0xff);
#else
                        Cb[(size_t)gr * DIM_H + (gc - DIM_QK)] = f2bf(v);
#endif
                    }
                } else if (MODE == 1) {
                    Cb[(size_t)gr * ldc + gc] = f2bf(v);
                } else {
                    Cf[(size_t)gr * ldc + gc] = v;
                }
            }
        }
}

// ---------------- prep ----------------
__global__ void zero_deg(int* __restrict__ deg) {
    int i = blockIdx.x * blockDim.x + threadIdx.x;
    if (i < N_NODES) deg[i] = 0;
}

// Fused: edge bucket-scatter, x cast, weight transpose/cast, qkv bias concat.
__global__ void prep_all(const float* __restrict__ x, const int* __restrict__ ei,
                         const float* __restrict__ W_in,
                         const float* __restrict__ Wq, const float* __restrict__ Wk,
                         const float* __restrict__ Wv,
                         const float* __restrict__ bq, const float* __restrict__ bk,
                         const float* __restrict__ bv,
                         const float* __restrict__ W1, const float* __restrict__ W2,
                         int* __restrict__ deg, int* __restrict__ col,
                         unsigned short* __restrict__ xb,
                         unsigned short* __restrict__ WinT, unsigned short* __restrict__ WqkvT,
                         unsigned short* __restrict__ W1T, unsigned short* __restrict__ W2T,
                         float* __restrict__ bqkv)
{
    int i = blockIdx.x * blockDim.x + threadIdx.x;
    int stride = gridDim.x * blockDim.x;
    for (int e = i; e < N_EDGES; e += stride) {
        int src = ei[e];
        int dst = ei[N_EDGES + e];
        int slot = atomicAdd(&deg[src], 1);
        if (slot < MAXD) col[src * MAXD + slot] = dst;
    }
    for (int idx = i; idx < (N_NODES * DIM_IN) / 8; idx += stride) {
        float4 a = ((const float4*)x)[2 * idx];
        float4 b = ((const float4*)x)[2 * idx + 1];
        uint4 o;
        o.x = (uint32_t)f2bf(a.x) | ((uint32_t)f2bf(a.y) << 16);
        o.y = (uint32_t)f2bf(a.z) | ((uint32_t)f2bf(a.w) << 16);
        o.z = (uint32_t)f2bf(b.x) | ((uint32_t)f2bf(b.y) << 16);
        o.w = (uint32_t)f2bf(b.z) | ((uint32_t)f2bf(b.w) << 16);
        ((uint4*)xb)[idx] = o;
    }
    for (int idx = i; idx < DIM_H * DIM_IN; idx += stride) {        // WinT [256][128]
        int n = idx / DIM_IN, k = idx % DIM_IN;
        WinT[idx] = f2bf(W_in[k * DIM_H + n]);
    }
    for (int idx = i; idx < DIM_QKV * DIM_H; idx += stride) {       // WqkvT [320][256]
        int n = idx / DIM_H, k = idx % DIM_H;
        float v = (n < DIM_C)     ? Wq[k * DIM_C + n]
                : (n < 2 * DIM_C) ? Wk[k * DIM_C + (n - DIM_C)]
                                  : Wv[k * DIM_H + (n - 2 * DIM_C)];
        WqkvT[idx] = f2bf(v);
    }
    for (int idx = i; idx < DIM_H * DIM_CAT; idx += stride) {       // W1T [256][512]
        int n = idx / DIM_CAT, k = idx % DIM_CAT;
        W1T[idx] = f2bf(W1[k * DIM_H + n]);
    }
    for (int idx = i; idx < DIM_OUT * DIM_H; idx += stride) {       // W2T [64][256]
        int n = idx / DIM_H, k = idx % DIM_H;
        W2T[idx] = f2bf(W2[k * DIM_OUT + n]);
    }
    for (int idx = i; idx < DIM_QKV; idx += stride)
        bqkv[idx] = (idx < DIM_C) ? bq[idx]
                  : (idx < 2 * DIM_C) ? bk[idx - DIM_C] : bv[idx - 2 * DIM_C];
}

// Fused per-row attention: dedup + q.k score + softmax + weighted v-gather -> bf16 comm.
// One wave per row, 4 rows per block. v table: fp8 e4m3 x VSCALE (or bf16 fallback).
__global__ __launch_bounds__(256)
void attn_row(const float* __restrict__ qk, const unsigned short* __restrict__ v_tab,
              const int* __restrict__ deg, const int* __restrict__ col,
              unsigned short* __restrict__ cat_bf) {
    __shared__ int   dstS[4][MAXD];
    __shared__ float wS[4][MAXD];
    __shared__ float qS[4][DIM_C];
    const int wave = threadIdx.x >> 6;
    const int lane = threadIdx.x & 63;
    const int row = blockIdx.x * 4 + wave;   // grid is exactly N_NODES/4
    int d = deg[row];
    if (d > MAXD) d = MAXD;
    const int* crow = col + (size_t)row * MAXD;

    // phase 1: stage neighbor ids + q row into LDS
    for (int p = lane; p < d; p += 64) dstS[wave][p] = crow[p];
    if (lane < DIM_C) qS[wave][lane] = qk[(size_t)row * DIM_QK + lane];
    __syncthreads();

    // phase 2: dedup (first instance wins) + exp(score)
    float mysum = 0.f;
    if (d <= 64) {
        int mydst = (lane < d) ? dstS[wave][lane] : -1;
        bool dup = false;
        #pragma unroll
        for (int k = 0; k < 63; ++k) {
            int other = __shfl(mydst, k, 64);
            dup = dup || (k < lane && other == mydst);
        }
        float w = 0.f;
        if (lane < d && !dup) {
            const float4* kp = (const float4*)(qk + (size_t)mydst * DIM_QK + DIM_C);
            float s = 0.f;
            #pragma unroll
            for (int i = 0; i < DIM_C / 4; ++i) {
                float4 b = kp[i];
                s += qS[wave][4 * i + 0] * b.x + qS[wave][4 * i + 1] * b.y
                   + qS[wave][4 * i + 2] * b.z + qS[wave][4 * i + 3] * b.w;
            }
            w = expf(s * SCALE);
        }
        wS[wave][lane] = w;
        mysum = w;
    } else {
        for (int p = lane; p < d; p += 64) {
            int mydst = dstS[wave][p];
            bool dup = false;
            for (int j = 0; j < p; ++j) dup = dup || (dstS[wave][j] == mydst);
            float w = 0.f;
            if (!dup) {
                const float4* kp = (const float4*)(qk + (size_t)mydst * DIM_QK + DIM_C);
                float s = 0.f;
                #pragma unroll
                for (int i = 0; i < DIM_C / 4; ++i) {
                    float4 b = kp[i];
                    s += qS[wave][4 * i + 0] * b.x + qS[wave][4 * i + 1] * b.y
                       + qS[wave][4 * i + 2] * b.z + qS[wave][4 * i + 3] * b.w;
                }
                w = expf(s * SCALE);
            }
            wS[wave][p] = w;
            mysum += w;
        }
    }
    #pragma unroll
    for (int off = 32; off; off >>= 1) mysum += __shfl_down(mysum, off, 64);
    float total = __shfl(mysum, 0, 64);
#if V_FP8
    float inv = (d > 0 && total > 0.f) ? 1.0f / (total * VSCALE) : 0.f;
#else
    float inv = (d > 0 && total > 0.f) ? 1.0f / total : 0.f;
#endif
    __syncthreads();

    // phase 3: comm[row] = inv * sum_p w_p * v[dst_p]; lane owns 4 of 256 cols.
    // Branch-free 16-wide unroll: 16 independent gathers in flight per latency window.
    float4 acc = make_float4(0.f, 0.f, 0.f, 0.f);
#if V_FP8
    const uint32_t* vb = (const uint32_t*)v_tab;     // fp8 row = 64 dwords
#else
    const uint2* vb = (const uint2*)v_tab;           // bf16 row = 64 uint2
#endif
    for (int p0 = 0; p0 < d; p0 += 16) {
        int j[16]; float w[16];
        #pragma unroll
        for (int t = 0; t < 16; ++t) {
            int idx = p0 + t;
            bool in = idx < d;
            j[t] = in ? dstS[wave][idx] : 0;        // pad: row 0 (L2-hot), weight 0
            w[t] = in ? wS[wave][idx] : 0.f;
        }
#if V_FP8
        uint32_t r[16];
        #pragma unroll
        for (int t = 0; t < 16; ++t) r[t] = vb[(size_t)j[t] * 64 + lane];
        #pragma unroll
        for (int t = 0; t < 16; ++t) {
            floatx2 lo = __builtin_amdgcn_cvt_pk_f32_fp8(r[t], false);
            floatx2 hi = __builtin_amdgcn_cvt_pk_f32_fp8(r[t], true);
            acc.x += w[t] * lo.x; acc.y += w[t] * lo.y;
            acc.z += w[t] * hi.x; acc.w += w[t] * hi.y;
        }
#else
        uint2 r[16];
        #pragma unroll
        for (int t = 0; t < 16; ++t) r[t] = vb[(size_t)j[t] * 64 + lane];
        #pragma unroll
        for (int t = 0; t < 16; ++t) {
            acc.x += w[t] * bf2f_lo(r[t].x);
            acc.y += w[t] * bf2f_hi(r[t].x);
            acc.z += w[t] * bf2f_lo(r[t].y);
            acc.w += w[t] * bf2f_hi(r[t].y);
        }
#endif
    }
    acc.x *= inv; acc.y *= inv; acc.z *= inv; acc.w *= inv;
    uint2 o;
    o.x = (uint32_t)f2bf(acc.x) | ((uint32_t)f2bf(acc.y) << 16);
    o.y = (uint32_t)f2bf(acc.z) | ((uint32_t)f2bf(acc.w) << 16);
    *(uint2*)(cat_bf + (size_t)row * DIM_CAT + DIM_H + lane * 4) = o;
}

// ---------------- launcher ----------------
extern "C" void kernel_launch(void* const* d_in, const int* in_sizes, int n_in,
                              void* d_out, int out_size, void* d_ws, size_t ws_size,
                              hipStream_t stream) {
    (void)in_sizes; (void)n_in; (void)out_size; (void)ws_size;
    const float* x    = (const float*)d_in[0];
    const int*   ei   = (const int*)d_in[1];
    const float* W_in = (const float*)d_in[2];
    const float* b_in = (const float*)d_in[3];
    const float* Wq   = (const float*)d_in[4];
    const float* bq   = (const float*)d_in[5];
    const float* Wk   = (const float*)d_in[6];
    const float* bk   = (const float*)d_in[7];
    const float* Wv   = (const float*)d_in[8];
    const float* bv   = (const float*)d_in[9];
    const float* W1   = (const float*)d_in[10];
    const float* b1   = (const float*)d_in[11];
    const float* W2   = (const float*)d_in[12];
    const float* b2   = (const float*)d_in[13];
    float* out = (float*)d_out;

    uint32_t* ws      = (uint32_t*)d_ws;
    int*      deg     = (int*)(ws + OFF_DEG);
    int*      col     = (int*)(ws + OFF_COL);
    float*    qk      = (float*)(ws + OFF_QK);
    float*    bqkv    = (float*)(ws + OFF_BQKV);
    unsigned short* v_tab  = (unsigned short*)(ws + OFF_VBF);   // fp8 or bf16 per V_FP8
    unsigned short* x_bf   = (unsigned short*)(ws + OFF_XBF);
    unsigned short* cat_bf = (unsigned short*)(ws + OFF_CATBF);
    unsigned short* z_bf   = (unsigned short*)(ws + OFF_ZBF);
    unsigned short* WinT   = (unsigned short*)(ws + OFF_WINT);
    unsigned short* WqkvT  = (unsigned short*)(ws + OFF_WQKVT);
    unsigned short* W1T    = (unsigned short*)(ws + OFF_W1T);
    unsigned short* W2T    = (unsigned short*)(ws + OFF_W2T);

    // 0) zero deg, then fused prep (edge bucket-scatter + casts + transposes)
    zero_deg<<<(N_NODES + 255) / 256, 256, 0, stream>>>(deg);
    prep_all<<<640, 256, 0, stream>>>(x, ei, W_in, Wq, Wk, Wv, bq, bk, bv, W1, W2,
                                      deg, col, x_bf, WinT, WqkvT, W1T, W2T, bqkv);

    const int MB = (N_NODES + 127) / 128;   // 79 row-blocks
    // 1) h = x@W_in + b_in -> bf16 cat[:,0:256]
    mfma_gemm<false, 1><<<dim3(DIM_H / 64, MB), 256, 0, stream>>>(
        x_bf, DIM_IN, WinT, b_in, nullptr, cat_bf, DIM_CAT, N_NODES, DIM_IN);
    // 2) qkv = h@[Wq|Wk|Wv] + b -> split: qk fp32 [N][64], v fp8/bf16 [N][256]
    mfma_gemm<false, 2><<<dim3(DIM_QKV / 64, MB), 256, 0, stream>>>(
        cat_bf, DIM_CAT, WqkvT, bqkv, qk, v_tab, 0, N_NODES, DIM_H);
    // 3) fused sparse attention (dedup + softmax + v-gather)
    attn_row<<<N_NODES / 4, 256, 0, stream>>>(qk, v_tab, deg, col, cat_bf);
    // 4) z = relu(cat@W1 + b1) -> bf16
    mfma_gemm<true, 1><<<dim3(DIM_H / 64, MB), 256, 0, stream>>>(
        cat_bf, DIM_CAT, W1T, b1, nullptr, z_bf, DIM_H, N_NODES, DIM_CAT);
    // 5) out = z@W2 + b2 -> fp32
    mfma_gemm<false, 0><<<dim3(DIM_OUT / 64, MB), 256, 0, stream>>>(
        z_bf, DIM_H, W2T, b2, out, nullptr, DIM_OUT, N_NODES, DIM_H);
}

// Round 10
// 178.044 us; speedup vs baseline: 1.3887x; 1.0082x over previous
//
#include <hip/hip_runtime.h>
#include <stdint.h>
#include <stddef.h>

// Problem constants (fixed by the reference).
constexpr int N_NODES = 10000;
constexpr int N_EDGES = 320000;
constexpr int DIM_IN  = 128;
constexpr int DIM_H   = 256;
constexpr int DIM_C   = 32;
constexpr int DIM_OUT = 64;
constexpr int DIM_QKV = DIM_C + DIM_C + DIM_H;  // 320 : [q|k|v]
constexpr int DIM_QK  = 2 * DIM_C;              // 64  : [q|k] compact fp32
constexpr int DIM_CAT = 2 * DIM_H;              // 512 : [h|comm]
constexpr float SCALE = 0.17677669529663687f;   // 1/sqrt(32)
constexpr int MAXD = 192;   // bucket capacity; Binomial(320k,1e-4) max ~66 (28 sigma margin)
constexpr float VSCALE = 64.0f;                 // fp8 v pre-scale (|v|max ~0.5 -> ~32 << 448)

#if __has_builtin(__builtin_amdgcn_cvt_pk_f32_fp8) && __has_builtin(__builtin_amdgcn_cvt_pk_fp8_f32)
#define V_FP8 1
#else
#define V_FP8 0   // fallback: bf16 v (round-8 proven path)
#endif

// ---------------- workspace layout (4-byte words) ----------------
constexpr size_t alignw(size_t w) { return (w + 15) & ~size_t(15); }
constexpr size_t OFF_DEG    = 0;
constexpr size_t OFF_COL    = alignw(OFF_DEG + N_NODES);                 // [N][MAXD] bucket
constexpr size_t OFF_QK     = alignw(OFF_COL + (size_t)N_NODES * MAXD);  // fp32 [N][64]
constexpr size_t OFF_BQKV   = alignw(OFF_QK + (size_t)N_NODES * DIM_QK);
// v region sized for the larger (bf16) variant; fp8 uses half of it.
constexpr size_t OFF_VBF    = alignw(OFF_BQKV + DIM_QKV);                       // [N][256]
constexpr size_t OFF_XBF    = alignw(OFF_VBF + (size_t)N_NODES * DIM_H / 2);    // [N][128]
constexpr size_t OFF_CATBF  = alignw(OFF_XBF + (size_t)N_NODES * DIM_IN / 2);   // [N][512]
constexpr size_t OFF_WINT   = alignw(OFF_CATBF + (size_t)N_NODES * DIM_CAT / 2);// [256][128]
constexpr size_t OFF_WQKVT  = alignw(OFF_WINT + (size_t)DIM_H * DIM_IN / 2);    // [320][256]
constexpr size_t OFF_W1T    = alignw(OFF_WQKVT + (size_t)DIM_QKV * DIM_H / 2);  // [256][512]
constexpr size_t OFF_W2T    = alignw(OFF_W1T + (size_t)DIM_H * DIM_CAT / 2);    // [64][256]
// total ≈ 32 MB (ws is 256 MiB)

typedef __attribute__((ext_vector_type(8))) short short8;
typedef __attribute__((ext_vector_type(4))) float floatx4;
typedef __attribute__((ext_vector_type(2))) float floatx2;

__device__ inline unsigned short f2bf(float f) {
    uint32_t u = __builtin_bit_cast(uint32_t, f);
    uint32_t r = (u + 0x7fffu + ((u >> 16) & 1u)) >> 16;   // RNE
    return (unsigned short)r;
}
__device__ inline float bf2f_lo(uint32_t u) { return __builtin_bit_cast(float, u << 16); }
__device__ inline float bf2f_hi(uint32_t u) { return __builtin_bit_cast(float, u & 0xffff0000u); }

// ---------------- bf16 MFMA GEMM:  C = A @ Bt^T + bias ---------------- (round-8 proven)
// MODE: 1 = bf16 out (ldc), 2 = qkv split (cols<64 -> fp32 qk[N][64],
//       cols>=64 -> v table: fp8 (V_FP8) or bf16, [N][256]).
template <bool RELU, int MODE>
__global__ __launch_bounds__(256)
void mfma_gemm(const unsigned short* __restrict__ A, int lda,
               const unsigned short* __restrict__ Bt,
               const float* __restrict__ bias,
               float* __restrict__ Cf, unsigned short* __restrict__ Cb, int ldc,
               int M, int K)
{
    constexpr int BM = 128, BN = 64, PAD = 40;   // +8 bf16 pad: 2-way banks max
    __shared__ short As[BM * PAD];
    __shared__ short Bs[BN * PAD];
    const int tid   = threadIdx.x;
    const int wave  = tid >> 6;
    const int lane  = tid & 63;
    const int quad  = lane >> 4;
    const int col16 = lane & 15;
    const int row0  = blockIdx.y * BM;
    const int col0  = blockIdx.x * BN;

    floatx4 acc[2][4] = {};

    const int sr = tid >> 2;          // staging row 0..63
    const int sc = (tid & 3) * 8;     // staging k-chunk offset (8 bf16 = 16B)

    for (int k0 = 0; k0 < K; k0 += 32) {
        #pragma unroll
        for (int i = 0; i < 2; ++i) {            // A tile: 128 rows x 32 k
            int r = sr + i * 64;
            int gr = row0 + r;
            short8 v = {};
            if (gr < M) v = *(const short8*)(A + (size_t)gr * lda + k0 + sc);
            *(short8*)(As + r * PAD + sc) = v;
        }
        {                                         // B tile: 64 n-rows x 32 k
            short8 v = *(const short8*)(Bt + (size_t)(col0 + sr) * K + k0 + sc);
            *(short8*)(Bs + sr * PAD + sc) = v;
        }
        __syncthreads();
        short8 a0 = *(const short8*)(As + (wave * 32 + col16) * PAD + quad * 8);
        short8 a1 = *(const short8*)(As + (wave * 32 + 16 + col16) * PAD + quad * 8);
        #pragma unroll
        for (int nf = 0; nf < 4; ++nf) {
            short8 b = *(const short8*)(Bs + (nf * 16 + col16) * PAD + quad * 8);
            acc[0][nf] = __builtin_amdgcn_mfma_f32_16x16x32_bf16(a0, b, acc[0][nf], 0, 0, 0);
            acc[1][nf] = __builtin_amdgcn_mfma_f32_16x16x32_bf16(a1, b, acc[1][nf], 0, 0, 0);
        }
        __syncthreads();
    }
    #pragma unroll
    for (int mf = 0; mf < 2; ++mf)
        #pragma unroll
        for (int r = 0; r < 4; ++r) {
            int gr = row0 + wave * 32 + mf * 16 + quad * 4 + r;
            if (gr >= M) continue;
            #pragma unroll
            for (int nf = 0; nf < 4; ++nf) {
                int gc = col0 + nf * 16 + col16;
                float v = acc[mf][nf][r] + bias[gc];
                if (RELU) v = fmaxf(v, 0.f);
                if (MODE == 2) {
                    if (gc < DIM_QK) {
                        Cf[(size_t)gr * DIM_QK + gc] = v;
                    } else {
#if V_FP8
                        int pk = __builtin_amdgcn_cvt_pk_fp8_f32(v * VSCALE, 0.f, 0, false);
                        ((unsigned char*)Cb)[(size_t)gr * DIM_H + (gc - DIM_QK)] =
                            (unsigned char)(pk & 0xff);
#else
                        Cb[(size_t)gr * DIM_H + (gc - DIM_QK)] = f2bf(v);
#endif
                    }
                } else {
                    Cb[(size_t)gr * ldc + gc] = f2bf(v);
                }
            }
        }
}

// ---------------- fused W1(relu) + W2 GEMM: out = relu(cat@W1+b1)@W2 + b2 ----------------
// BM=64 rows/block, K1=512, z (64x256) never leaves the CU: phase-A acc regs -> LDS tile
// (aliasing the dead B-staging buffer; total LDS 38.4 KB -> 4 blocks/CU) -> phase-B MFMA
// against W2T (32 KB, L2-hot). Grid = 157 blocks.
__global__ __launch_bounds__(256)
void gemm_w1w2(const unsigned short* __restrict__ cat, const unsigned short* __restrict__ W1T,
               const float* __restrict__ b1, const unsigned short* __restrict__ W2T,
               const float* __restrict__ b2, float* __restrict__ out, int M)
{
    constexpr int PAD = 40, TP = 260;   // Ts row stride (bf16)
    __shared__ short As[64 * PAD];                 // 5,120 B
    __shared__ short BsTs[64 * TP];                // 33,280 B: Bs (256*40=10,240 sh) aliases Ts
    short* Bs = BsTs;
    short* Ts = BsTs;
    const int tid   = threadIdx.x;
    const int wave  = tid >> 6;
    const int lane  = tid & 63;
    const int quad  = lane >> 4;
    const int col16 = lane & 15;
    const int row0  = blockIdx.x * 64;

    const int sr = tid >> 2;          // 0..63
    const int sc = (tid & 3) * 8;     // 16B k-chunk

    // ---- phase A: z = relu(cat @ W1T^T + b1), 64 rows x 256 cols ----
    floatx4 acc[16] = {};
    for (int k0 = 0; k0 < DIM_CAT; k0 += 32) {
        {   // A tile: 64 rows x 32 k
            int gr = row0 + sr;
            short8 v = {};
            if (gr < M) v = *(const short8*)(cat + (size_t)gr * DIM_CAT + k0 + sc);
            *(short8*)(As + sr * PAD + sc) = v;
        }
        #pragma unroll
        for (int p = 0; p < 4; ++p) {  // B tile: 256 n-rows x 32 k
            int r = sr + p * 64;
            *(short8*)(Bs + r * PAD + sc) = *(const short8*)(W1T + (size_t)r * DIM_CAT + k0 + sc);
        }
        __syncthreads();
        short8 a = *(const short8*)(As + (wave * 16 + col16) * PAD + quad * 8);
        #pragma unroll
        for (int nf = 0; nf < 16; ++nf) {
            short8 b = *(const short8*)(Bs + (nf * 16 + col16) * PAD + quad * 8);
            acc[nf] = __builtin_amdgcn_mfma_f32_16x16x32_bf16(a, b, acc[nf], 0, 0, 0);
        }
        __syncthreads();   // all Bs reads done before next staging (and before Ts overwrite)
    }

    // epilogue A: bias + relu -> bf16 z tile in Ts (aliases Bs; safe after final barrier)
    #pragma unroll
    for (int nf = 0; nf < 16; ++nf) {
        int gc = nf * 16 + col16;
        float bia = b1[gc];
        #pragma unroll
        for (int r = 0; r < 4; ++r) {
            int lr = wave * 16 + quad * 4 + r;
            float v = fmaxf(acc[nf][r] + bia, 0.f);
            Ts[lr * TP + gc] = (short)f2bf(v);
        }
    }
    __syncthreads();

    // ---- phase B: out = z @ W2T^T + b2, K=256, N=64 ----
    floatx4 acc2[4] = {};
    for (int k0 = 0; k0 < DIM_H; k0 += 32) {
        short8 a = *(const short8*)(Ts + (wave * 16 + col16) * TP + k0 + quad * 8);
        #pragma unroll
        for (int nf = 0; nf < 4; ++nf) {
            int brow = nf * 16 + col16;
            short8 b = *(const short8*)(W2T + (size_t)brow * DIM_H + k0 + quad * 8);
            acc2[nf] = __builtin_amdgcn_mfma_f32_16x16x32_bf16(a, b, acc2[nf], 0, 0, 0);
        }
    }
    #pragma unroll
    for (int nf = 0; nf < 4; ++nf) {
        int gc = nf * 16 + col16;
        float bia = b2[gc];
        #pragma unroll
        for (int r = 0; r < 4; ++r) {
            int gr = row0 + wave * 16 + quad * 4 + r;
            if (gr < M) out[(size_t)gr * DIM_OUT + gc] = acc2[nf][r] + bia;
        }
    }
}

// ---------------- prep ----------------
__global__ void zero_deg(int* __restrict__ deg) {
    int i = blockIdx.x * blockDim.x + threadIdx.x;
    if (i < N_NODES) deg[i] = 0;
}

// Fused: edge bucket-scatter, x cast, weight transpose/cast, qkv bias concat.
__global__ void prep_all(const float* __restrict__ x, const int* __restrict__ ei,
                         const float* __restrict__ W_in,
                         const float* __restrict__ Wq, const float* __restrict__ Wk,
                         const float* __restrict__ Wv,
                         const float* __restrict__ bq, const float* __restrict__ bk,
                         const float* __restrict__ bv,
                         const float* __restrict__ W1, const float* __restrict__ W2,
                         int* __restrict__ deg, int* __restrict__ col,
                         unsigned short* __restrict__ xb,
                         unsigned short* __restrict__ WinT, unsigned short* __restrict__ WqkvT,
                         unsigned short* __restrict__ W1T, unsigned short* __restrict__ W2T,
                         float* __restrict__ bqkv)
{
    int i = blockIdx.x * blockDim.x + threadIdx.x;
    int stride = gridDim.x * blockDim.x;
    for (int e = i; e < N_EDGES; e += stride) {
        int src = ei[e];
        int dst = ei[N_EDGES + e];
        int slot = atomicAdd(&deg[src], 1);
        if (slot < MAXD) col[src * MAXD + slot] = dst;
    }
    for (int idx = i; idx < (N_NODES * DIM_IN) / 8; idx += stride) {
        float4 a = ((const float4*)x)[2 * idx];
        float4 b = ((const float4*)x)[2 * idx + 1];
        uint4 o;
        o.x = (uint32_t)f2bf(a.x) | ((uint32_t)f2bf(a.y) << 16);
        o.y = (uint32_t)f2bf(a.z) | ((uint32_t)f2bf(a.w) << 16);
        o.z = (uint32_t)f2bf(b.x) | ((uint32_t)f2bf(b.y) << 16);
        o.w = (uint32_t)f2bf(b.z) | ((uint32_t)f2bf(b.w) << 16);
        ((uint4*)xb)[idx] = o;
    }
    for (int idx = i; idx < DIM_H * DIM_IN; idx += stride) {        // WinT [256][128]
        int n = idx / DIM_IN, k = idx % DIM_IN;
        WinT[idx] = f2bf(W_in[k * DIM_H + n]);
    }
    for (int idx = i; idx < DIM_QKV * DIM_H; idx += stride) {       // WqkvT [320][256]
        int n = idx / DIM_H, k = idx % DIM_H;
        float v = (n < DIM_C)     ? Wq[k * DIM_C + n]
                : (n < 2 * DIM_C) ? Wk[k * DIM_C + (n - DIM_C)]
                                  : Wv[k * DIM_H + (n - 2 * DIM_C)];
        WqkvT[idx] = f2bf(v);
    }
    for (int idx = i; idx < DIM_H * DIM_CAT; idx += stride) {       // W1T [256][512]
        int n = idx / DIM_CAT, k = idx % DIM_CAT;
        W1T[idx] = f2bf(W1[k * DIM_H + n]);
    }
    for (int idx = i; idx < DIM_OUT * DIM_H; idx += stride) {       // W2T [64][256]
        int n = idx / DIM_H, k = idx % DIM_H;
        W2T[idx] = f2bf(W2[k * DIM_OUT + n]);
    }
    for (int idx = i; idx < DIM_QKV; idx += stride)
        bqkv[idx] = (idx < DIM_C) ? bq[idx]
                  : (idx < 2 * DIM_C) ? bk[idx - DIM_C] : bv[idx - 2 * DIM_C];
}

// Fused per-row attention: dedup + q.k score + softmax + weighted v-gather -> bf16 comm.
// One wave per row, 4 rows per block. v table: fp8 e4m3 x VSCALE (or bf16 fallback).
__global__ __launch_bounds__(256)
void attn_row(const float* __restrict__ qk, const unsigned short* __restrict__ v_tab,
              const int* __restrict__ deg, const int* __restrict__ col,
              unsigned short* __restrict__ cat_bf) {
    __shared__ int   dstS[4][MAXD];
    __shared__ float wS[4][MAXD];
    __shared__ float qS[4][DIM_C];
    const int wave = threadIdx.x >> 6;
    const int lane = threadIdx.x & 63;
    const int row = blockIdx.x * 4 + wave;   // grid is exactly N_NODES/4
    int d = deg[row];
    if (d > MAXD) d = MAXD;
    const int* crow = col + (size_t)row * MAXD;

    // phase 1: stage neighbor ids + q row into LDS
    for (int p = lane; p < d; p += 64) dstS[wave][p] = crow[p];
    if (lane < DIM_C) qS[wave][lane] = qk[(size_t)row * DIM_QK + lane];
    __syncthreads();

    // phase 2: dedup (first instance wins) + exp(score)
    float mysum = 0.f;
    if (d <= 64) {
        int mydst = (lane < d) ? dstS[wave][lane] : -1;
        bool dup = false;
        #pragma unroll
        for (int k = 0; k < 63; ++k) {
            int other = __shfl(mydst, k, 64);
            dup = dup || (k < lane && other == mydst);
        }
        float w = 0.f;
        if (lane < d && !dup) {
            const float4* kp = (const float4*)(qk + (size_t)mydst * DIM_QK + DIM_C);
            float s = 0.f;
            #pragma unroll
            for (int i = 0; i < DIM_C / 4; ++i) {
                float4 b = kp[i];
                s += qS[wave][4 * i + 0] * b.x + qS[wave][4 * i + 1] * b.y
                   + qS[wave][4 * i + 2] * b.z + qS[wave][4 * i + 3] * b.w;
            }
            w = expf(s * SCALE);
        }
        wS[wave][lane] = w;
        mysum = w;
    } else {
        for (int p = lane; p < d; p += 64) {
            int mydst = dstS[wave][p];
            bool dup = false;
            for (int j = 0; j < p; ++j) dup = dup || (dstS[wave][j] == mydst);
            float w = 0.f;
            if (!dup) {
                const float4* kp = (const float4*)(qk + (size_t)mydst * DIM_QK + DIM_C);
                float s = 0.f;
                #pragma unroll
                for (int i = 0; i < DIM_C / 4; ++i) {
                    float4 b = kp[i];
                    s += qS[wave][4 * i + 0] * b.x + qS[wave][4 * i + 1] * b.y
                       + qS[wave][4 * i + 2] * b.z + qS[wave][4 * i + 3] * b.w;
                }
                w = expf(s * SCALE);
            }
            wS[wave][p] = w;
            mysum += w;
        }
    }
    #pragma unroll
    for (int off = 32; off; off >>= 1) mysum += __shfl_down(mysum, off, 64);
    float total = __shfl(mysum, 0, 64);
#if V_FP8
    float inv = (d > 0 && total > 0.f) ? 1.0f / (total * VSCALE) : 0.f;
#else
    float inv = (d > 0 && total > 0.f) ? 1.0f / total : 0.f;
#endif
    __syncthreads();

    // phase 3: comm[row] = inv * sum_p w_p * v[dst_p]; lane owns 4 of 256 cols.
    // Branch-free 16-wide unroll: 16 independent gathers in flight per latency window.
    float4 acc = make_float4(0.f, 0.f, 0.f, 0.f);
#if V_FP8
    const uint32_t* vb = (const uint32_t*)v_tab;     // fp8 row = 64 dwords
#else
    const uint2* vb = (const uint2*)v_tab;           // bf16 row = 64 uint2
#endif
    for (int p0 = 0; p0 < d; p0 += 16) {
        int j[16]; float w[16];
        #pragma unroll
        for (int t = 0; t < 16; ++t) {
            int idx = p0 + t;
            bool in = idx < d;
            j[t] = in ? dstS[wave][idx] : 0;        // pad: row 0 (L2-hot), weight 0
            w[t] = in ? wS[wave][idx] : 0.f;
        }
#if V_FP8
        uint32_t r[16];
        #pragma unroll
        for (int t = 0; t < 16; ++t) r[t] = vb[(size_t)j[t] * 64 + lane];
        #pragma unroll
        for (int t = 0; t < 16; ++t) {
            floatx2 lo = __builtin_amdgcn_cvt_pk_f32_fp8(r[t], false);
            floatx2 hi = __builtin_amdgcn_cvt_pk_f32_fp8(r[t], true);
            acc.x += w[t] * lo.x; acc.y += w[t] * lo.y;
            acc.z += w[t] * hi.x; acc.w += w[t] * hi.y;
        }
#else
        uint2 r[16];
        #pragma unroll
        for (int t = 0; t < 16; ++t) r[t] = vb[(size_t)j[t] * 64 + lane];
        #pragma unroll
        for (int t = 0; t < 16; ++t) {
            acc.x += w[t] * bf2f_lo(r[t].x);
            acc.y += w[t] * bf2f_hi(r[t].x);
            acc.z += w[t] * bf2f_lo(r[t].y);
            acc.w += w[t] * bf2f_hi(r[t].y);
        }
#endif
    }
    acc.x *= inv; acc.y *= inv; acc.z *= inv; acc.w *= inv;
    uint2 o;
    o.x = (uint32_t)f2bf(acc.x) | ((uint32_t)f2bf(acc.y) << 16);
    o.y = (uint32_t)f2bf(acc.z) | ((uint32_t)f2bf(acc.w) << 16);
    *(uint2*)(cat_bf + (size_t)row * DIM_CAT + DIM_H + lane * 4) = o;
}

// ---------------- launcher ----------------
extern "C" void kernel_launch(void* const* d_in, const int* in_sizes, int n_in,
                              void* d_out, int out_size, void* d_ws, size_t ws_size,
                              hipStream_t stream) {
    (void)in_sizes; (void)n_in; (void)out_size; (void)ws_size;
    const float* x    = (const float*)d_in[0];
    const int*   ei   = (const int*)d_in[1];
    const float* W_in = (const float*)d_in[2];
    const float* b_in = (const float*)d_in[3];
    const float* Wq   = (const float*)d_in[4];
    const float* bq   = (const float*)d_in[5];
    const float* Wk   = (const float*)d_in[6];
    const float* bk   = (const float*)d_in[7];
    const float* Wv   = (const float*)d_in[8];
    const float* bv   = (const float*)d_in[9];
    const float* W1   = (const float*)d_in[10];
    const float* b1   = (const float*)d_in[11];
    const float* W2   = (const float*)d_in[12];
    const float* b2   = (const float*)d_in[13];
    float* out = (float*)d_out;

    uint32_t* ws      = (uint32_t*)d_ws;
    int*      deg     = (int*)(ws + OFF_DEG);
    int*      col     = (int*)(ws + OFF_COL);
    float*    qk      = (float*)(ws + OFF_QK);
    float*    bqkv    = (float*)(ws + OFF_BQKV);
    unsigned short* v_tab  = (unsigned short*)(ws + OFF_VBF);   // fp8 or bf16 per V_FP8
    unsigned short* x_bf   = (unsigned short*)(ws + OFF_XBF);
    unsigned short* cat_bf = (unsigned short*)(ws + OFF_CATBF);
    unsigned short* WinT   = (unsigned short*)(ws + OFF_WINT);
    unsigned short* WqkvT  = (unsigned short*)(ws + OFF_WQKVT);
    unsigned short* W1T    = (unsigned short*)(ws + OFF_W1T);
    unsigned short* W2T    = (unsigned short*)(ws + OFF_W2T);

    // 0) zero deg, then fused prep (edge bucket-scatter + casts + transposes)
    zero_deg<<<(N_NODES + 255) / 256, 256, 0, stream>>>(deg);
    prep_all<<<640, 256, 0, stream>>>(x, ei, W_in, Wq, Wk, Wv, bq, bk, bv, W1, W2,
                                      deg, col, x_bf, WinT, WqkvT, W1T, W2T, bqkv);

    const int MB = (N_NODES + 127) / 128;   // 79 row-blocks
    // 1) h = x@W_in + b_in -> bf16 cat[:,0:256]
    mfma_gemm<false, 1><<<dim3(DIM_H / 64, MB), 256, 0, stream>>>(
        x_bf, DIM_IN, WinT, b_in, nullptr, cat_bf, DIM_CAT, N_NODES, DIM_IN);
    // 2) qkv = h@[Wq|Wk|Wv] + b -> split: qk fp32 [N][64], v fp8/bf16 [N][256]
    mfma_gemm<false, 2><<<dim3(DIM_QKV / 64, MB), 256, 0, stream>>>(
        cat_bf, DIM_CAT, WqkvT, bqkv, qk, v_tab, 0, N_NODES, DIM_H);
    // 3) fused sparse attention (dedup + softmax + v-gather)
    attn_row<<<N_NODES / 4, 256, 0, stream>>>(qk, v_tab, deg, col, cat_bf);
    // 4+5) out = relu(cat@W1+b1)@W2 + b2, z kept on-CU
    gemm_w1w2<<<(N_NODES + 63) / 64, 256, 0, stream>>>(
        cat_bf, W1T, b1, W2T, b2, out, N_NODES);
}